// Round 6
// baseline (254.017 us; speedup 1.0000x reference)
//
#include <hip/hip_runtime.h>
#include <hip/hip_bf16.h>

#define B_ 4
#define C_ 256
#define N_ 4096
#define K_ 16
#define FSCALE 1.2011224087864498f   // sqrt(log2(e)) -> QK^T comes out in log2 domain

typedef float f32x4 __attribute__((ext_vector_type(4)));
typedef float f32x16 __attribute__((ext_vector_type(16)));
typedef short s16x8 __attribute__((ext_vector_type(8)));
typedef int   i32x4 __attribute__((ext_vector_type(4)));
typedef int   i32x2 __attribute__((ext_vector_type(2)));

__device__ __forceinline__ short f2bf(float f) {
  union { float f; unsigned u; } v; v.f = f;
  unsigned r = v.u + 0x7fffu + ((v.u >> 16) & 1u);
  return (short)(r >> 16);
}
__device__ __forceinline__ int packbf(float a, float b) {
  __hip_bfloat162 h = __float22bfloat162_rn(make_float2(a, b));
  int r; __builtin_memcpy(&r, &h, 4); return r;
}
#if __has_builtin(__builtin_amdgcn_exp2f)
__device__ __forceinline__ float fexp2(float x) { return __builtin_amdgcn_exp2f(x); }
#else
__device__ __forceinline__ float fexp2(float x) { return exp2f(x); }
#endif

// ---------------- pass 1: f = (w1*x + b1)*FSCALE -> fT bf16 [b][n][16]; xb = bf16(x) ----------------
__global__ __launch_bounds__(256) void prep(const float* __restrict__ x,
                                            const float* __restrict__ w1,
                                            const float* __restrict__ b1,
                                            short* __restrict__ xb,
                                            short* __restrict__ fT) {
  __shared__ float w1t[C_ * K_];
  __shared__ float pr[4][64][17];
  for (int i = threadIdx.x; i < C_ * K_; i += 256) {
    int k = i >> 8, c = i & 255;
    w1t[c * K_ + k] = w1[i];
  }
  __syncthreads();
  const int blk = blockIdx.x;
  const int b = blk >> 6;
  const int n0 = (blk & 63) * 64;
  const int t = threadIdx.x;
  const int nl = t & 63;
  const int cch = t >> 6;
  const int n = n0 + nl;
  const float* xp = x + (size_t)b * C_ * N_ + n;
  short* xbp = xb + (size_t)b * C_ * N_ + n;
  float acc[K_];
#pragma unroll
  for (int k = 0; k < K_; k++) acc[k] = 0.f;
  for (int cc = 0; cc < 64; cc++) {
    int c = cch * 64 + cc;
    float v = xp[(size_t)c * N_];
    xbp[(size_t)c * N_] = f2bf(v);
    const f32x4* wp = (const f32x4*)(&w1t[c * K_]);
#pragma unroll
    for (int qq = 0; qq < 4; qq++) {
      f32x4 wv = wp[qq];
#pragma unroll
      for (int j = 0; j < 4; j++) acc[qq * 4 + j] += wv[j] * v;
    }
  }
#pragma unroll
  for (int k = 0; k < K_; k++) pr[cch][nl][k] = acc[k];
  __syncthreads();
#pragma unroll
  for (int jj = 0; jj < 4; jj++) {
    int o = t + jj * 256;
    int on = o >> 4, ok = o & 15;
    float s = pr[0][on][ok] + pr[1][on][ok] + pr[2][on][ok] + pr[3][on][ok] + b1[ok];
    fT[((size_t)b * N_ + n0 + on) * K_ + ok] = f2bf(s * FSCALE);
  }
}

// ---------------- pass 2: barrier-free flash. V read from L2 per-fragment; no LDS in main loop. ----
// Wave = (cs: 64-channel span, h: m-half). Block = 8 waves, n-span 32 (one MFMA tile).
// Grid 512, id->(b,nt) swizzled so XCD (id&7) maps to batch b=(id>>1)&3: each XCD's L2 streams
// only its own xb[b] (2MB < 4MB).
// No running max (R5-verified bound: P <= ~2^94, L >= 1, all inside f32).
// PV k-permutation folded into per-lane global addresses: frag (st,kc), lane (q,hi):
//   chunkA = xb[c][m0 + st*32+kc*16+hi*4 + 0..3], chunkB = +8 shorts.
__global__ __launch_bounds__(512) void flash2(const float* __restrict__ x,
                                              const short* __restrict__ xb,
                                              const short* __restrict__ fT,
                                              float* __restrict__ out) {
  __shared__ __align__(16) char lds[34816];   // epilogue exchange only
  const int tid = threadIdx.x;
  const int l = tid & 63;
  const int wu = tid >> 6;   // 0..7
  const int cs = wu & 3;
  const int h = wu >> 2;     // m-half
  const int q = l & 31;
  const int hi = l >> 5;
  const int id = blockIdx.x;
  const int b = (id >> 1) & 3;
  const int nt = ((id >> 3) << 1) | (id & 1);
  const int n0 = nt * 32;

  const short* fTb = fT + (size_t)b * N_ * K_;
  const short* xbb = xb + (size_t)b * C_ * N_;

  s16x8 qf = *(const s16x8*)(fTb + (n0 + q) * K_ + hi * 8);

  const short* pk = fTb + (h * 2048 + q) * K_ + hi * 8;
  const int c0 = cs * 64 + q;
  const short* pv0 = xbb + (size_t)c0 * N_ + h * 2048 + hi * 4;
  const short* pv1 = pv0 + 32 * (size_t)N_;

  f32x16 zero16 = {};
  f32x16 acc0 = zero16, acc1 = zero16;
  float lrun = 0.f;

  for (int it = 0; it < 32; ++it) {
    // ---- V fragment loads (16 x 8B); issued first so latency hides under QK/softmax ----
    i32x2 va0[4], vb0[4], va1[4], vb1[4];   // frag f = st*2 + kc
#pragma unroll
    for (int f = 0; f < 4; ++f) {
      const int off = (f >> 1) * 32 + (f & 1) * 16;   // shorts: st*32 + kc*16
      va0[f] = *(const i32x2*)(pv0 + off);
      vb0[f] = *(const i32x2*)(pv0 + off + 8);
      va1[f] = *(const i32x2*)(pv1 + off);
      vb1[f] = *(const i32x2*)(pv1 + off + 8);
    }
    s16x8 kf0 = *(const s16x8*)(pk);
    s16x8 kf1 = *(const s16x8*)(pk + 32 * K_);

    // ---- QK^T: S'[m][n] (log2 domain), two 32x32 tiles ----
    f32x16 st0 = __builtin_amdgcn_mfma_f32_32x32x16_bf16(kf0, qf, zero16, 0, 0, 0);
    f32x16 st1 = __builtin_amdgcn_mfma_f32_32x32x16_bf16(kf1, qf, zero16, 0, 0, 0);

    // ---- P = exp2(S') directly; 4 parallel sum chains ----
    float ps0 = 0.f, ps1 = 0.f, ps2 = 0.f, ps3 = 0.f;
#pragma unroll
    for (int r = 0; r < 16; r += 4) {
      st0[r] = fexp2(st0[r]);         ps0 += st0[r];
      st0[r + 1] = fexp2(st0[r + 1]); ps1 += st0[r + 1];
      st0[r + 2] = fexp2(st0[r + 2]); ps2 += st0[r + 2];
      st0[r + 3] = fexp2(st0[r + 3]); ps3 += st0[r + 3];
    }
#pragma unroll
    for (int r = 0; r < 16; r += 4) {
      st1[r] = fexp2(st1[r]);         ps0 += st1[r];
      st1[r + 1] = fexp2(st1[r + 1]); ps1 += st1[r + 1];
      st1[r + 2] = fexp2(st1[r + 2]); ps2 += st1[r + 2];
      st1[r + 3] = fexp2(st1[r + 3]); ps3 += st1[r + 3];
    }
    lrun += (ps0 + ps1) + (ps2 + ps3);

    // ---- pack P to bf16 ----
    int sd0[8], sd1[8];
#pragma unroll
    for (int s2 = 0; s2 < 8; s2++) {
      sd0[s2] = packbf(st0[2 * s2], st0[2 * s2 + 1]);
      sd1[s2] = packbf(st1[2 * s2], st1[2 * s2 + 1]);
    }

    // ---- PV: O^T[c][n] += V~[c][k] * P~[k][n] (k-perm consistent on both sides) ----
#pragma unroll
    for (int kc = 0; kc < 2; ++kc) {
      {
        const int f = 0 * 2 + kc;  // st0
        i32x4 pi = {sd0[4 * kc], sd0[4 * kc + 1], sd0[4 * kc + 2], sd0[4 * kc + 3]};
        s16x8 pf = __builtin_bit_cast(s16x8, pi);
        i32x4 v0 = {va0[f][0], va0[f][1], vb0[f][0], vb0[f][1]};
        acc0 = __builtin_amdgcn_mfma_f32_32x32x16_bf16(__builtin_bit_cast(s16x8, v0), pf, acc0, 0, 0, 0);
        i32x4 v1 = {va1[f][0], va1[f][1], vb1[f][0], vb1[f][1]};
        acc1 = __builtin_amdgcn_mfma_f32_32x32x16_bf16(__builtin_bit_cast(s16x8, v1), pf, acc1, 0, 0, 0);
      }
      {
        const int f = 1 * 2 + kc;  // st1
        i32x4 pi = {sd1[4 * kc], sd1[4 * kc + 1], sd1[4 * kc + 2], sd1[4 * kc + 3]};
        s16x8 pf = __builtin_bit_cast(s16x8, pi);
        i32x4 v0 = {va0[f][0], va0[f][1], vb0[f][0], vb0[f][1]};
        acc0 = __builtin_amdgcn_mfma_f32_32x32x16_bf16(__builtin_bit_cast(s16x8, v0), pf, acc0, 0, 0, 0);
        i32x4 v1 = {va1[f][0], va1[f][1], vb1[f][0], vb1[f][1]};
        acc1 = __builtin_amdgcn_mfma_f32_32x32x16_bf16(__builtin_bit_cast(s16x8, v1), pf, acc1, 0, 0, 0);
      }
    }
    pk += 64 * K_;     // next 64 m-rows of fT
    pv0 += 64;         // next 64 m of xb (128B)
    pv1 += 64;
  }

  // column-sum across hi halves (each lane summed only its hi-subset of rows)
  lrun += __shfl_xor(lrun, 32);

  // ---------------- single-barrier h-merge + epilogue ----------------
  float* lb = (float*)lds;               // [8 waves][64 lanes]
  float* ex = (float*)(lds + 2048);      // [writer h][cs][16 regs][64 lanes]
  lb[wu * 64 + l] = lrun;
#pragma unroll
  for (int r = 0; r < 16; ++r)
    ex[(h * 4 + cs) * 1024 + r * 64 + l] = h ? acc0[r] : acc1[r];
  __syncthreads();
  const float L = lrun + lb[(wu ^ 4) * 64 + l];
  const float invL = 0.1f / L;
  const int n = n0 + q;
  // h0 finalizes c-tile 0 (own acc0 + partner acc0); h1 finalizes c-tile 1.
#pragma unroll
  for (int p_ = 0; p_ < 4; ++p_) {
#pragma unroll
    for (int r = 0; r < 4; ++r) {
      const int rr = p_ * 4 + r;
      const float own = h ? acc1[rr] : acc0[rr];
      const float part = ex[((h ^ 1) * 4 + cs) * 1024 + rr * 64 + l];
      const int c = cs * 64 + h * 32 + p_ * 8 + hi * 4 + r;
      const size_t idx = ((size_t)b * C_ + c) * N_ + n;
      out[idx] = x[idx] + (own + part) * invL;
    }
  }
}

extern "C" void kernel_launch(void* const* d_in, const int* in_sizes, int n_in,
                              void* d_out, int out_size, void* d_ws, size_t ws_size,
                              hipStream_t stream) {
  const float* x  = (const float*)d_in[0];
  const float* w1 = (const float*)d_in[1];
  const float* b1 = (const float*)d_in[2];
  float* out = (float*)d_out;
  short* xb = (short*)d_ws;                                      // [B][C][N] bf16, 8MB
  short* fT = (short*)((char*)d_ws + (size_t)B_ * C_ * N_ * 2);  // [B][N][16] bf16, 512KB
  prep<<<dim3(256), dim3(256), 0, stream>>>(x, w1, b1, xb, fT);
  flash2<<<dim3(512), dim3(512), 0, stream>>>(x, xb, fT, out);
}

// Round 7
// 140.121 us; speedup vs baseline: 1.8128x; 1.8128x over previous
//
#include <hip/hip_runtime.h>
#include <hip/hip_bf16.h>

#define B_ 4
#define C_ 256
#define N_ 4096
#define K_ 16
#define FSCALE 1.2011224087864498f   // sqrt(log2(e)) -> QK^T comes out in log2 domain

typedef float f32x4 __attribute__((ext_vector_type(4)));
typedef float f32x16 __attribute__((ext_vector_type(16)));
typedef short s16x8 __attribute__((ext_vector_type(8)));
typedef int   i32x4 __attribute__((ext_vector_type(4)));
typedef int   i32x2 __attribute__((ext_vector_type(2)));

__device__ __forceinline__ short f2bf(float f) {
  union { float f; unsigned u; } v; v.f = f;
  unsigned r = v.u + 0x7fffu + ((v.u >> 16) & 1u);
  return (short)(r >> 16);
}
__device__ __forceinline__ int packbf(float a, float b) {
  __hip_bfloat162 h = __float22bfloat162_rn(make_float2(a, b));
  int r; __builtin_memcpy(&r, &h, 4); return r;
}
#if __has_builtin(__builtin_amdgcn_exp2f)
__device__ __forceinline__ float fexp2(float x) { return __builtin_amdgcn_exp2f(x); }
#else
__device__ __forceinline__ float fexp2(float x) { return exp2f(x); }
#endif

// ---------------- pass 1: f = (w1*x + b1)*FSCALE -> fT bf16 [b][n][16] ----------------
__global__ __launch_bounds__(256) void prep(const float* __restrict__ x,
                                            const float* __restrict__ w1,
                                            const float* __restrict__ b1,
                                            short* __restrict__ fT) {
  __shared__ float w1t[C_ * K_];
  __shared__ float pr[4][64][17];
  for (int i = threadIdx.x; i < C_ * K_; i += 256) {
    int k = i >> 8, c = i & 255;
    w1t[c * K_ + k] = w1[i];
  }
  __syncthreads();
  const int blk = blockIdx.x;
  const int b = blk >> 6;
  const int n0 = (blk & 63) * 64;
  const int t = threadIdx.x;
  const int nl = t & 63;
  const int cch = t >> 6;
  const int n = n0 + nl;
  const float* xp = x + (size_t)b * C_ * N_ + n;
  float acc[K_];
#pragma unroll
  for (int k = 0; k < K_; k++) acc[k] = 0.f;
  for (int cc = 0; cc < 64; cc++) {
    int c = cch * 64 + cc;
    float v = xp[(size_t)c * N_];
    const f32x4* wp = (const f32x4*)(&w1t[c * K_]);
#pragma unroll
    for (int qq = 0; qq < 4; qq++) {
      f32x4 wv = wp[qq];
#pragma unroll
      for (int j = 0; j < 4; j++) acc[qq * 4 + j] += wv[j] * v;
    }
  }
#pragma unroll
  for (int k = 0; k < K_; k++) pr[cch][nl][k] = acc[k];
  __syncthreads();
#pragma unroll
  for (int jj = 0; jj < 4; jj++) {
    int o = t + jj * 256;
    int on = o >> 4, ok = o & 15;
    float s = pr[0][on][ok] + pr[1][on][ok] + pr[2][on][ok] + pr[3][on][ok] + b1[ok];
    fT[((size_t)b * N_ + n0 + on) * K_ + ok] = f2bf(s * FSCALE);
  }
}

// ---------------- pass 1b: pack V: xbG[b][m>>3][c][m&7] bf16 (16B = 8 m per (mg,c)) ----------------
__global__ __launch_bounds__(256) void packv(const float* __restrict__ x,
                                             short* __restrict__ xbG) {
  __shared__ short t[64 * 136];  // [c-local 64][n-local 128 + 8 pad], 272B rows, XOR-swizzled 16B blocks
  const int bid = blockIdx.x;    // 512 = 4b x 4cb x 32nb
  const int b = bid >> 7, cb = (bid >> 5) & 3, nb = bid & 31;
  const int n0 = nb * 128, c0 = cb * 64;
  const int tid = threadIdx.x;
  const int r = tid >> 2, cg = tid & 3;
  const float* xp = x + ((size_t)(b * 256 + c0 + r)) * N_ + n0 + cg * 32;
#pragma unroll
  for (int k = 0; k < 8; k++) {
    f32x4 v = *(const f32x4*)(xp + k * 4);
    i32x2 p = {packbf(v[0], v[1]), packbf(v[2], v[3])};
    int col = (cg * 32 + k * 4) ^ ((r & 7) * 8);   // swizzle in short units (8-short = 16B blocks)
    *(i32x2*)(&t[r * 136 + col]) = p;
  }
  __syncthreads();
#pragma unroll
  for (int u = 0; u < 4; u++) {
    int chunk = tid + 256 * u;
    int mg = chunk >> 6, c = chunk & 63;
    s16x8 vv = *(const s16x8*)(&t[c * 136 + ((mg * 8) ^ ((c & 7) * 8))]);
    *(s16x8*)(xbG + (((size_t)b * 512 + (n0 >> 3) + mg) * 256 + c0 + c) * 8) = vv;
  }
}

// ---------------- pass 2: flash, V straight from L2 (coalesced via xbG), P via blocked LDS ----------
// 8 waves; wave j: production role (nt_p=j>>2, t_p=(j>>1)&1, kc_p=j&1) + PV c-span j*32.
// Per iter (64 m): 1 QK MFMA, 8 exps, P-quarter -> LDS (2 x b64, contiguous), 1 barrier,
// 8 pf b128 (contiguous) + 4 vf global (2x512B dense segments) -> 8 PV MFMA into acc[nt] (D[n][c]).
// No running max (R5-verified bound: P <= ~2^94, L >= 1, all inside f32).
__global__ __launch_bounds__(512) void flash3(const float* __restrict__ x,
                                              const short* __restrict__ xbG,
                                              const short* __restrict__ fT,
                                              float* __restrict__ out) {
  __shared__ __align__(16) char lds[18944];  // P dbuf 2x8192 + lrun 2048 + L 256
  const int tid = threadIdx.x;
  const int l = tid & 63;
  const int j = tid >> 6;
  const int q = l & 31;
  const int hi = l >> 5;
  const int id = blockIdx.x;
  const int b = id & 3;                                // XCD x=id&7 -> batch b=x&3 (L2 locality)
  const int nblk = ((id >> 3) << 1) | ((id >> 2) & 1); // bijective
  const int n0g = nblk * 64;
  const int nt_p = j >> 2, t_p = (j >> 1) & 1, kc_p = j & 1;
  const int s_p = 2 * t_p + kc_p;

  const short* fTb = fT + (size_t)b * N_ * K_;
  const s16x8 qf = *(const s16x8*)(fTb + (n0g + nt_p * 32 + q) * K_ + hi * 8);
  const short* pkb = fTb + (t_p * 32 + q) * K_ + hi * 8;          // +1024 shorts per iter
  const short* pvb = xbG + (size_t)b * 1048576 + hi * 2048 + (j * 32 + q) * 8;  // +16384/iter, +4096/s

  char* Pw1 = lds + ((nt_p * 8 + s_p * 2) * 32 + q) * 16 + hi * 8;  // [nt][s][hi_r=0][q] + hi_p*8
  char* Prd = lds + q * 16;                                          // + (nt*8+s*2+hi)*512

  f32x16 zero16 = {};
  f32x16 acc0 = zero16, acc1 = zero16;
  float lrun = 0.f;

  s16x8 kf = *(const s16x8*)(pkb);
  s16x8 vf0 = *(const s16x8*)(pvb);
  s16x8 vf1 = *(const s16x8*)(pvb + 4096);
  s16x8 vf2 = *(const s16x8*)(pvb + 8192);
  s16x8 vf3 = *(const s16x8*)(pvb + 12288);

  for (int it = 0; it < 64; ++it) {
    const int flip = (it & 1) * 8192;
    const int itn = (it < 63) ? it + 1 : it;   // clamped prefetch (last re-read, discarded)
    s16x8 kfn = *(const s16x8*)(pkb + itn * 1024);
    const short* pvn = pvb + itn * 16384;
    s16x8 nf0 = *(const s16x8*)(pvn);
    s16x8 nf1 = *(const s16x8*)(pvn + 4096);
    s16x8 nf2 = *(const s16x8*)(pvn + 8192);
    s16x8 nf3 = *(const s16x8*)(pvn + 12288);

    // QK: S'[m-tile t_p][n-tile nt_p] in log2 domain
    f32x16 st = __builtin_amdgcn_mfma_f32_32x32x16_bf16(kf, qf, zero16, 0, 0, 0);

    // exp2 of this wave's 8 regs (kc half), pack, write P-quarter (wave-uniform branch)
    float e0, e1, e2, e3, e4, e5, e6, e7;
    if (kc_p == 0) {
      e0 = fexp2(st[0]); e1 = fexp2(st[1]); e2 = fexp2(st[2]); e3 = fexp2(st[3]);
      e4 = fexp2(st[4]); e5 = fexp2(st[5]); e6 = fexp2(st[6]); e7 = fexp2(st[7]);
    } else {
      e0 = fexp2(st[8]);  e1 = fexp2(st[9]);  e2 = fexp2(st[10]); e3 = fexp2(st[11]);
      e4 = fexp2(st[12]); e5 = fexp2(st[13]); e6 = fexp2(st[14]); e7 = fexp2(st[15]);
    }
    lrun += ((e0 + e1) + (e2 + e3)) + ((e4 + e5) + (e6 + e7));
    i32x2 c1 = {packbf(e0, e1), packbf(e2, e3)};
    i32x2 c2 = {packbf(e4, e5), packbf(e6, e7)};
    *(i32x2*)(Pw1 + flip) = c1;
    *(i32x2*)(Pw1 + flip + 512) = c2;

    __syncthreads();

    // PV: acc[nt] (D[n][c]) += P~[n][k] * V~[k][c]
#pragma unroll
    for (int s = 0; s < 4; ++s) {
      s16x8 vfs = (s == 0) ? vf0 : (s == 1) ? vf1 : (s == 2) ? vf2 : vf3;
      s16x8 pf0 = *(const s16x8*)(Prd + flip + (0 * 8 + s * 2 + hi) * 512);
      acc0 = __builtin_amdgcn_mfma_f32_32x32x16_bf16(pf0, vfs, acc0, 0, 0, 0);
      s16x8 pf1 = *(const s16x8*)(Prd + flip + (1 * 8 + s * 2 + hi) * 512);
      acc1 = __builtin_amdgcn_mfma_f32_32x32x16_bf16(pf1, vfs, acc1, 0, 0, 0);
    }
    kf = kfn; vf0 = nf0; vf1 = nf1; vf2 = nf2; vf3 = nf3;
  }

  // ---------------- L merge + epilogue ----------------
  float* lds_l = (float*)(lds + 16384);   // [8 waves][64 lanes]
  float* L_lds = (float*)(lds + 18432);   // [64 n-local] = 0.1/L
  __syncthreads();                        // P buffers done
  lds_l[j * 64 + l] = lrun;
  __syncthreads();
  if (tid < 64) {
    const int nt = tid >> 5, qq = tid & 31;
    float L = 0.f;
#pragma unroll
    for (int w = 0; w < 4; ++w) {
      const int ww = nt * 4 + w;
      L += lds_l[ww * 64 + qq] + lds_l[ww * 64 + 32 + qq];
    }
    L_lds[tid] = 0.1f / L;
  }
  __syncthreads();

  const int c = j * 32 + q;
  const float* xr = x + ((size_t)(b * 256 + c)) * N_ + n0g;
  float* outw = out + ((size_t)(b * 256 + c)) * N_ + n0g;
#pragma unroll
  for (int nt = 0; nt < 2; ++nt) {
#pragma unroll
    for (int s = 0; s < 4; ++s) {
      const int nl = nt * 32 + 8 * s + 4 * hi;
      f32x4 iv = *(const f32x4*)(&L_lds[nl]);
      f32x4 xq = *(const f32x4*)(xr + nl);
      f32x4 ov;
#pragma unroll
      for (int u = 0; u < 4; ++u) {
        const float a = nt ? acc1[4 * s + u] : acc0[4 * s + u];
        ov[u] = xq[u] + a * iv[u];
      }
      *(f32x4*)(outw + nl) = ov;
    }
  }
}

extern "C" void kernel_launch(void* const* d_in, const int* in_sizes, int n_in,
                              void* d_out, int out_size, void* d_ws, size_t ws_size,
                              hipStream_t stream) {
  const float* x  = (const float*)d_in[0];
  const float* w1 = (const float*)d_in[1];
  const float* b1 = (const float*)d_in[2];
  float* out = (float*)d_out;
  short* fT  = (short*)d_ws;                                  // [B][N][16] bf16, 512KB
  short* xbG = (short*)((char*)d_ws + 512 * 1024);            // [B][512][256][8] bf16, 8MB
  prep<<<dim3(256), dim3(256), 0, stream>>>(x, w1, b1, fT);
  packv<<<dim3(512), dim3(256), 0, stream>>>(x, xbG);
  flash3<<<dim3(256), dim3(512), 0, stream>>>(x, xbG, fT, out);
}

// Round 8
// 87.968 us; speedup vs baseline: 2.8876x; 1.5929x over previous
//
#include <hip/hip_runtime.h>
#include <hip/hip_bf16.h>

#define B_ 4
#define C_ 256
#define N_ 4096
#define K_ 16
#define QB 64
#define FSCALE 1.2011224087864498f   // sqrt(log2(e)) -> QK^T comes out in log2 domain

typedef float f32x4 __attribute__((ext_vector_type(4)));
typedef float f32x16 __attribute__((ext_vector_type(16)));
typedef short s16x8 __attribute__((ext_vector_type(8)));
typedef int   i32x4 __attribute__((ext_vector_type(4)));
typedef int   i32x2 __attribute__((ext_vector_type(2)));

__device__ __forceinline__ short f2bf(float f) {
  union { float f; unsigned u; } v; v.f = f;
  unsigned r = v.u + 0x7fffu + ((v.u >> 16) & 1u);
  return (short)(r >> 16);
}
__device__ __forceinline__ int packbf(float a, float b) {
  __hip_bfloat162 h = __float22bfloat162_rn(make_float2(a, b));
  int r; __builtin_memcpy(&r, &h, 4); return r;
}
#if __has_builtin(__builtin_amdgcn_exp2f)
__device__ __forceinline__ float fexp2(float x) { return __builtin_amdgcn_exp2f(x); }
#else
__device__ __forceinline__ float fexp2(float x) { return exp2f(x); }
#endif

// ---------------- pass 1: f = (w1*x + b1)*FSCALE -> fT bf16 [b][n][16] ----------------
__global__ __launch_bounds__(256) void prep(const float* __restrict__ x,
                                            const float* __restrict__ w1,
                                            const float* __restrict__ b1,
                                            short* __restrict__ fT) {
  __shared__ float w1t[C_ * K_];
  __shared__ float pr[4][64][17];
  for (int i = threadIdx.x; i < C_ * K_; i += 256) {
    int k = i >> 8, c = i & 255;
    w1t[c * K_ + k] = w1[i];
  }
  __syncthreads();
  const int blk = blockIdx.x;
  const int b = blk >> 6;
  const int n0 = (blk & 63) * 64;
  const int t = threadIdx.x;
  const int nl = t & 63;
  const int cch = t >> 6;
  const int n = n0 + nl;
  const float* xp = x + (size_t)b * C_ * N_ + n;
  float acc[K_];
#pragma unroll
  for (int k = 0; k < K_; k++) acc[k] = 0.f;
  for (int cc = 0; cc < 64; cc++) {
    int c = cch * 64 + cc;
    float v = xp[(size_t)c * N_];
    const f32x4* wp = (const f32x4*)(&w1t[c * K_]);
#pragma unroll
    for (int qq = 0; qq < 4; qq++) {
      f32x4 wv = wp[qq];
#pragma unroll
      for (int j = 0; j < 4; j++) acc[qq * 4 + j] += wv[j] * v;
    }
  }
#pragma unroll
  for (int k = 0; k < K_; k++) pr[cch][nl][k] = acc[k];
  __syncthreads();
#pragma unroll
  for (int jj = 0; jj < 4; jj++) {
    int o = t + jj * 256;
    int on = o >> 4, ok = o & 15;
    float s = pr[0][on][ok] + pr[1][on][ok] + pr[2][on][ok] + pr[3][on][ok] + b1[ok];
    fT[((size_t)b * N_ + n0 + on) * K_ + ok] = f2bf(s * FSCALE);
  }
}

// ---- pass 1b: pack V with the PV k-permutation baked in ----
// vtP[b][g][c][8] bf16, g = 2*m16 + hi (m16 = m>>4), element j holds
// V[c][16*m16 + 4*hi + (j&3) + 8*(j>>2)] — exactly one MFMA A-fragment per 16B.
__global__ __launch_bounds__(256) void packv(const float* __restrict__ x,
                                             short* __restrict__ vtP) {
  __shared__ short t[64 * 136];  // [c-local 64][m-local 128 + pad], XOR-swizzled 8-short blocks
  const int bid = blockIdx.x;    // 512 = 4b x 4cb x 32nb
  const int b = bid >> 7, cb = (bid >> 5) & 3, nb = bid & 31;
  const int n0 = nb * 128, c0 = cb * 64;
  const int tid = threadIdx.x;
  const int r = tid >> 2, cg = tid & 3;
  const float* xp = x + ((size_t)(b * 256 + c0 + r)) * N_ + n0 + cg * 32;
#pragma unroll
  for (int k = 0; k < 8; k++) {
    f32x4 v = *(const f32x4*)(xp + k * 4);
    i32x2 p = {packbf(v[0], v[1]), packbf(v[2], v[3])};
    int col = (cg * 32 + k * 4) ^ ((r & 7) * 8);
    *(i32x2*)(&t[r * 136 + col]) = p;
  }
  __syncthreads();
#pragma unroll
  for (int u = 0; u < 4; u++) {
    int chunk = tid + 256 * u;          // 1024 = 16 gl x 64 c
    int gl = chunk >> 6, c = chunk & 63;
    int m16 = gl >> 1, hi = gl & 1;
    int swz = (c & 7) * 8;
    i32x2 a = *(const i32x2*)(&t[c * 136 + ((m16 * 16 + hi * 4) ^ swz)]);
    i32x2 bq = *(const i32x2*)(&t[c * 136 + ((m16 * 16 + 8 + hi * 4) ^ swz)]);
    i32x4 vv = {a[0], a[1], bq[0], bq[1]};
    size_t g = (size_t)b * 512 + (size_t)(nb * 8 + m16) * 2 + hi;
    *(i32x4*)(vtP + (g * 256 + c0 + c) * 8) = vv;
  }
}

// ---------------- pass 2: barrier-free flash (R5 wave structure + L2-direct permuted V) --------
// wave w: h = w>>3 (m-half), nt = (w&7)>>2 (32 n-cols), cs = w&3 (64-c span). Lane: q=l&31, hi=l>>5.
// Per iter (64 m): 2 QK MFMA -> 32 exp2 (no max; R5-verified bounds) -> pack -> 8 PV MFMA with
// V fragments loaded straight from vtP (16B/lane, coalesced, XCD-local L2). No LDS, no barriers.
__global__ __launch_bounds__(1024) void flash4(const float* __restrict__ x,
                                               const short* __restrict__ vtP,
                                               const short* __restrict__ fT,
                                               float* __restrict__ out) {
  __shared__ __align__(16) char lds[65536];   // epilogue h-merge only
  const int tid = threadIdx.x;
  const int l = tid & 63;
  const int w = tid >> 6;
  const int h = w >> 3;
  const int wu = w & 7;
  const int nt = wu >> 2;
  const int cs = wu & 3;
  const int hi = l >> 5;
  const int q = l & 31;
  const int id = blockIdx.x;
  const int b = id & 3;            // XCD (id&7) -> fixed batch (L2 locality: vtP[b] = 2MB < 4MB)
  const int n0 = (id >> 2) * QB;

  const short* fTb = fT + (size_t)b * N_ * K_;
  const int mh0 = h * 2048;

  const s16x8 qf = *(const s16x8*)(fTb + (size_t)(n0 + nt * 32 + q) * K_ + hi * 8);
  const short* pk = fTb + (size_t)(mh0 + q) * K_ + hi * 8;
  const short* pv = vtP + (((size_t)b * 512 + (mh0 >> 4) * 2 + hi) * 256 + cs * 64 + q) * 8;

  f32x16 zero16 = {};
  f32x16 acc0 = zero16, acc1 = zero16;
  float lrun = 0.f;

  for (int it = 0; it < 32; ++it) {
    // K fragments (fT is 128KB/batch — L2/L1-resident)
    s16x8 kf0 = *(const s16x8*)(pk);
    s16x8 kf1 = *(const s16x8*)(pk + 32 * K_);
    // V fragments: frag (ks, ct): one 16B load, lanes dense across q
    s16x8 vA0 = *(const s16x8*)(pv);
    s16x8 vB0 = *(const s16x8*)(pv + 256);
    s16x8 vA1 = *(const s16x8*)(pv + 4096);
    s16x8 vB1 = *(const s16x8*)(pv + 4096 + 256);
    s16x8 vA2 = *(const s16x8*)(pv + 8192);
    s16x8 vB2 = *(const s16x8*)(pv + 8192 + 256);
    s16x8 vA3 = *(const s16x8*)(pv + 12288);
    s16x8 vB3 = *(const s16x8*)(pv + 12288 + 256);

    // QK^T: S'[m][n] (log2 domain), two 32x32 tiles
    f32x16 st0 = __builtin_amdgcn_mfma_f32_32x32x16_bf16(kf0, qf, zero16, 0, 0, 0);
    f32x16 st1 = __builtin_amdgcn_mfma_f32_32x32x16_bf16(kf1, qf, zero16, 0, 0, 0);

    // P = exp2(S') directly; 4 parallel sum chains
    float ps0 = 0.f, ps1 = 0.f, ps2 = 0.f, ps3 = 0.f;
#pragma unroll
    for (int r = 0; r < 16; r += 4) {
      st0[r] = fexp2(st0[r]);         ps0 += st0[r];
      st0[r + 1] = fexp2(st0[r + 1]); ps1 += st0[r + 1];
      st0[r + 2] = fexp2(st0[r + 2]); ps2 += st0[r + 2];
      st0[r + 3] = fexp2(st0[r + 3]); ps3 += st0[r + 3];
    }
#pragma unroll
    for (int r = 0; r < 16; r += 4) {
      st1[r] = fexp2(st1[r]);         ps0 += st1[r];
      st1[r + 1] = fexp2(st1[r + 1]); ps1 += st1[r + 1];
      st1[r + 2] = fexp2(st1[r + 2]); ps2 += st1[r + 2];
      st1[r + 3] = fexp2(st1[r + 3]); ps3 += st1[r + 3];
    }
    lrun += (ps0 + ps1) + (ps2 + ps3);

    // pack P to bf16: sd_st[s] = (P[2s], P[2s+1])
    int sd0[8], sd1[8];
#pragma unroll
    for (int s2 = 0; s2 < 8; s2++) {
      sd0[s2] = packbf(st0[2 * s2], st0[2 * s2 + 1]);
      sd1[s2] = packbf(st1[2 * s2], st1[2 * s2 + 1]);
    }

    // PV: acc[ct] (O^T[c][n]) += V~[c][k] * P~[k][n]; ks = 2*st + kc, pf = sd_st[4kc..4kc+3]
    {
      i32x4 p0 = {sd0[0], sd0[1], sd0[2], sd0[3]};
      s16x8 pf = __builtin_bit_cast(s16x8, p0);
      acc0 = __builtin_amdgcn_mfma_f32_32x32x16_bf16(vA0, pf, acc0, 0, 0, 0);
      acc1 = __builtin_amdgcn_mfma_f32_32x32x16_bf16(vB0, pf, acc1, 0, 0, 0);
    }
    {
      i32x4 p1 = {sd0[4], sd0[5], sd0[6], sd0[7]};
      s16x8 pf = __builtin_bit_cast(s16x8, p1);
      acc0 = __builtin_amdgcn_mfma_f32_32x32x16_bf16(vA1, pf, acc0, 0, 0, 0);
      acc1 = __builtin_amdgcn_mfma_f32_32x32x16_bf16(vB1, pf, acc1, 0, 0, 0);
    }
    {
      i32x4 p2 = {sd1[0], sd1[1], sd1[2], sd1[3]};
      s16x8 pf = __builtin_bit_cast(s16x8, p2);
      acc0 = __builtin_amdgcn_mfma_f32_32x32x16_bf16(vA2, pf, acc0, 0, 0, 0);
      acc1 = __builtin_amdgcn_mfma_f32_32x32x16_bf16(vB2, pf, acc1, 0, 0, 0);
    }
    {
      i32x4 p3 = {sd1[4], sd1[5], sd1[6], sd1[7]};
      s16x8 pf = __builtin_bit_cast(s16x8, p3);
      acc0 = __builtin_amdgcn_mfma_f32_32x32x16_bf16(vA3, pf, acc0, 0, 0, 0);
      acc1 = __builtin_amdgcn_mfma_f32_32x32x16_bf16(vB3, pf, acc1, 0, 0, 0);
    }
    pk += 64 * K_;
    pv += 16384;
  }

  // hi-partner combine of l (purely additive)
  lrun += __shfl_xor(lrun, 32);

  // ---------------- merge the two m-halves + epilogue ----------------
  float* mlb = (float*)lds;             // [16 waves][64 lanes]
  mlb[w * 64 + l] = lrun;
  __syncthreads();
  const float L = lrun + mlb[(w ^ 8) * 64 + l];
  __syncthreads();
  char* xch = lds;                      // [8 wu][64 l][128B], swizzled
  const int xbase = (wu * 64 + l) * 128;
  if (h == 1) {
#pragma unroll
    for (int i = 0; i < 8; i++) {
      f32x4 v;
#pragma unroll
      for (int r = 0; r < 4; r++) v[r] = (i >> 2) ? acc1[(i & 3) * 4 + r] : acc0[(i & 3) * 4 + r];
      *(f32x4*)(xch + xbase + ((i * 16) ^ ((l & 7) << 4))) = v;
    }
  }
  __syncthreads();
  if (h == 0) {
    const float invL = 0.1f / L;
    const int n = n0 + nt * 32 + q;
#pragma unroll
    for (int i = 0; i < 8; i++) {
      f32x4 po = *(const f32x4*)(xch + xbase + ((i * 16) ^ ((l & 7) << 4)));
      const int p_ = i & 3;
      const int cbase = cs * 64 + (i >> 2) * 32 + p_ * 8 + hi * 4;
#pragma unroll
      for (int r = 0; r < 4; r++) {
        const float own = (i >> 2) ? acc1[p_ * 4 + r] : acc0[p_ * 4 + r];
        const size_t idx = ((size_t)b * C_ + (cbase + r)) * N_ + n;
        out[idx] = x[idx] + (own + po[r]) * invL;
      }
    }
  }
}

extern "C" void kernel_launch(void* const* d_in, const int* in_sizes, int n_in,
                              void* d_out, int out_size, void* d_ws, size_t ws_size,
                              hipStream_t stream) {
  const float* x  = (const float*)d_in[0];
  const float* w1 = (const float*)d_in[1];
  const float* b1 = (const float*)d_in[2];
  float* out = (float*)d_out;
  short* fT  = (short*)d_ws;                         // [B][N][16] bf16, 512KB
  short* vtP = (short*)((char*)d_ws + 512 * 1024);   // [B][512][256][8] bf16, 8MB
  prep<<<dim3(256), dim3(256), 0, stream>>>(x, w1, b1, fT);
  packv<<<dim3(512), dim3(256), 0, stream>>>(x, vtP);
  flash4<<<dim3(256), dim3(1024), 0, stream>>>(x, vtP, fT, out);
}

// Round 9
// 87.902 us; speedup vs baseline: 2.8898x; 1.0008x over previous
//
#include <hip/hip_runtime.h>
#include <hip/hip_bf16.h>

#define B_ 4
#define C_ 256
#define N_ 4096
#define K_ 16
#define QB 64
#define FSCALE 1.2011224087864498f   // sqrt(log2(e)) -> QK^T comes out in log2 domain

typedef float f32x4 __attribute__((ext_vector_type(4)));
typedef float f32x16 __attribute__((ext_vector_type(16)));
typedef short s16x8 __attribute__((ext_vector_type(8)));
typedef int   i32x4 __attribute__((ext_vector_type(4)));
typedef int   i32x2 __attribute__((ext_vector_type(2)));

__device__ __forceinline__ short f2bf(float f) {
  union { float f; unsigned u; } v; v.f = f;
  unsigned r = v.u + 0x7fffu + ((v.u >> 16) & 1u);
  return (short)(r >> 16);
}
__device__ __forceinline__ int packbf(float a, float b) {
  __hip_bfloat162 h = __float22bfloat162_rn(make_float2(a, b));
  int r; __builtin_memcpy(&r, &h, 4); return r;
}
#if __has_builtin(__builtin_amdgcn_exp2f)
__device__ __forceinline__ float fexp2(float x) { return __builtin_amdgcn_exp2f(x); }
#else
__device__ __forceinline__ float fexp2(float x) { return exp2f(x); }
#endif

// ---------------- pass 1: f = (w1*x + b1)*FSCALE -> fT bf16 [b][n][16] ----------------
__global__ __launch_bounds__(256) void prep(const float* __restrict__ x,
                                            const float* __restrict__ w1,
                                            const float* __restrict__ b1,
                                            short* __restrict__ fT) {
  __shared__ float w1t[C_ * K_];
  __shared__ float pr[4][64][17];
  for (int i = threadIdx.x; i < C_ * K_; i += 256) {
    int k = i >> 8, c = i & 255;
    w1t[c * K_ + k] = w1[i];
  }
  __syncthreads();
  const int blk = blockIdx.x;
  const int b = blk >> 6;
  const int n0 = (blk & 63) * 64;
  const int t = threadIdx.x;
  const int nl = t & 63;
  const int cch = t >> 6;
  const int n = n0 + nl;
  const float* xp = x + (size_t)b * C_ * N_ + n;
  float acc[K_];
#pragma unroll
  for (int k = 0; k < K_; k++) acc[k] = 0.f;
  for (int cc = 0; cc < 64; cc++) {
    int c = cch * 64 + cc;
    float v = xp[(size_t)c * N_];
    const f32x4* wp = (const f32x4*)(&w1t[c * K_]);
#pragma unroll
    for (int qq = 0; qq < 4; qq++) {
      f32x4 wv = wp[qq];
#pragma unroll
      for (int j = 0; j < 4; j++) acc[qq * 4 + j] += wv[j] * v;
    }
  }
#pragma unroll
  for (int k = 0; k < K_; k++) pr[cch][nl][k] = acc[k];
  __syncthreads();
#pragma unroll
  for (int jj = 0; jj < 4; jj++) {
    int o = t + jj * 256;
    int on = o >> 4, ok = o & 15;
    float s = pr[0][on][ok] + pr[1][on][ok] + pr[2][on][ok] + pr[3][on][ok] + b1[ok];
    fT[((size_t)b * N_ + n0 + on) * K_ + ok] = f2bf(s * FSCALE);
  }
}

// ---- pass 1b: pack V with the PV k-permutation baked in ----
// vtP[b][g][c][8] bf16, g = 2*m16 + hi (m16 = m>>4), element j holds
// V[c][16*m16 + 4*hi + (j&3) + 8*(j>>2)] — exactly one MFMA A-fragment per 16B.
__global__ __launch_bounds__(256) void packv(const float* __restrict__ x,
                                             short* __restrict__ vtP) {
  __shared__ short t[64 * 136];  // [c-local 64][m-local 128 + pad], XOR-swizzled 8-short blocks
  const int bid = blockIdx.x;    // 512 = 4b x 4cb x 32nb
  const int b = bid >> 7, cb = (bid >> 5) & 3, nb = bid & 31;
  const int n0 = nb * 128, c0 = cb * 64;
  const int tid = threadIdx.x;
  const int r = tid >> 2, cg = tid & 3;
  const float* xp = x + ((size_t)(b * 256 + c0 + r)) * N_ + n0 + cg * 32;
#pragma unroll
  for (int k = 0; k < 8; k++) {
    f32x4 v = *(const f32x4*)(xp + k * 4);
    i32x2 p = {packbf(v[0], v[1]), packbf(v[2], v[3])};
    int col = (cg * 32 + k * 4) ^ ((r & 7) * 8);
    *(i32x2*)(&t[r * 136 + col]) = p;
  }
  __syncthreads();
#pragma unroll
  for (int u = 0; u < 4; u++) {
    int chunk = tid + 256 * u;          // 1024 = 16 gl x 64 c
    int gl = chunk >> 6, c = chunk & 63;
    int m16 = gl >> 1, hi = gl & 1;
    int swz = (c & 7) * 8;
    i32x2 a = *(const i32x2*)(&t[c * 136 + ((m16 * 16 + hi * 4) ^ swz)]);
    i32x2 bq = *(const i32x2*)(&t[c * 136 + ((m16 * 16 + 8 + hi * 4) ^ swz)]);
    i32x4 vv = {a[0], a[1], bq[0], bq[1]};
    size_t g = (size_t)b * 512 + (size_t)(nb * 8 + m16) * 2 + hi;
    *(i32x4*)(vtP + (g * 256 + c0 + c) * 8) = vv;
  }
}

// ---------------- pass 2: barrier-free flash with rotated (1-deep) register prefetch -----------
// R8 structure; loads moved to their consumption points so no instruction waits on a young load:
//   QK(it) -> issue K(it+1) -> exp/pack (covers K) -> PV(it) -> issue V(it+1) (covered by next QK+exp)
__global__ __launch_bounds__(1024, 4) void flash5(const float* __restrict__ x,
                                                  const short* __restrict__ vtP,
                                                  const short* __restrict__ fT,
                                                  float* __restrict__ out) {
  __shared__ __align__(16) char lds[65536];   // epilogue h-merge only
  const int tid = threadIdx.x;
  const int l = tid & 63;
  const int w = tid >> 6;
  const int h = w >> 3;
  const int wu = w & 7;
  const int nt = wu >> 2;
  const int cs = wu & 3;
  const int hi = l >> 5;
  const int q = l & 31;
  const int id = blockIdx.x;
  const int b = id & 3;            // XCD (id&7) -> fixed batch (L2 locality: vtP[b] = 2MB < 4MB)
  const int n0 = (id >> 2) * QB;

  const short* fTb = fT + (size_t)b * N_ * K_;
  const int mh0 = h * 2048;

  const s16x8 qf = *(const s16x8*)(fTb + (size_t)(n0 + nt * 32 + q) * K_ + hi * 8);
  const short* pk = fTb + (size_t)(mh0 + q) * K_ + hi * 8;
  const short* pv = vtP + (((size_t)b * 512 + (mh0 >> 4) * 2 + hi) * 256 + cs * 64 + q) * 8;

  f32x16 zero16 = {};
  f32x16 acc0 = zero16, acc1 = zero16;
  float lrun = 0.f;

  // prologue: tile-0 operands
  s16x8 kf0 = *(const s16x8*)(pk);
  s16x8 kf1 = *(const s16x8*)(pk + 32 * K_);
  s16x8 vA0 = *(const s16x8*)(pv);
  s16x8 vB0 = *(const s16x8*)(pv + 256);
  s16x8 vA1 = *(const s16x8*)(pv + 4096);
  s16x8 vB1 = *(const s16x8*)(pv + 4096 + 256);
  s16x8 vA2 = *(const s16x8*)(pv + 8192);
  s16x8 vB2 = *(const s16x8*)(pv + 8192 + 256);
  s16x8 vA3 = *(const s16x8*)(pv + 12288);
  s16x8 vB3 = *(const s16x8*)(pv + 12288 + 256);

#pragma unroll 1
  for (int it = 0; it < 32; ++it) {
    const int adv = (it < 31) ? 1 : 0;           // clamp: last iter re-reads (discarded)
    const short* pkn = pk + adv * 1024;
    const short* pvn = pv + adv * 16384;

    // QK^T: S'[m][n] (log2 domain), two 32x32 tiles (consumes kf)
    f32x16 st0 = __builtin_amdgcn_mfma_f32_32x32x16_bf16(kf0, qf, zero16, 0, 0, 0);
    f32x16 st1 = __builtin_amdgcn_mfma_f32_32x32x16_bf16(kf1, qf, zero16, 0, 0, 0);

    // prefetch next K now; its latency is covered by exp/pack below
    s16x8 nk0 = *(const s16x8*)(pkn);
    s16x8 nk1 = *(const s16x8*)(pkn + 32 * K_);

    // P = exp2(S') directly (no max; R5-verified bounds), pack pairs immediately
    // (chunked so st registers die early -> keeps VGPR under the 4-wave cap)
    int sd0[8], sd1[8];
    float ps0 = 0.f, ps1 = 0.f, ps2 = 0.f, ps3 = 0.f;
#pragma unroll
    for (int s2 = 0; s2 < 8; s2++) {
      float a = fexp2(st0[2 * s2]);
      float bb = fexp2(st0[2 * s2 + 1]);
      ps0 += a; ps1 += bb;
      sd0[s2] = packbf(a, bb);
    }
#pragma unroll
    for (int s2 = 0; s2 < 8; s2++) {
      float a = fexp2(st1[2 * s2]);
      float bb = fexp2(st1[2 * s2 + 1]);
      ps2 += a; ps3 += bb;
      sd1[s2] = packbf(a, bb);
    }
    lrun += (ps0 + ps1) + (ps2 + ps3);

    // PV: acc[ct] (O^T[c][n]) += V~[c][k] * P~[k][n] (consumes vf; vf arrived last iter)
    {
      i32x4 p0 = {sd0[0], sd0[1], sd0[2], sd0[3]};
      s16x8 pf = __builtin_bit_cast(s16x8, p0);
      acc0 = __builtin_amdgcn_mfma_f32_32x32x16_bf16(vA0, pf, acc0, 0, 0, 0);
      acc1 = __builtin_amdgcn_mfma_f32_32x32x16_bf16(vB0, pf, acc1, 0, 0, 0);
    }
    {
      i32x4 p1 = {sd0[4], sd0[5], sd0[6], sd0[7]};
      s16x8 pf = __builtin_bit_cast(s16x8, p1);
      acc0 = __builtin_amdgcn_mfma_f32_32x32x16_bf16(vA1, pf, acc0, 0, 0, 0);
      acc1 = __builtin_amdgcn_mfma_f32_32x32x16_bf16(vB1, pf, acc1, 0, 0, 0);
    }
    {
      i32x4 p2 = {sd1[0], sd1[1], sd1[2], sd1[3]};
      s16x8 pf = __builtin_bit_cast(s16x8, p2);
      acc0 = __builtin_amdgcn_mfma_f32_32x32x16_bf16(vA2, pf, acc0, 0, 0, 0);
      acc1 = __builtin_amdgcn_mfma_f32_32x32x16_bf16(vB2, pf, acc1, 0, 0, 0);
    }
    {
      i32x4 p3 = {sd1[4], sd1[5], sd1[6], sd1[7]};
      s16x8 pf = __builtin_bit_cast(s16x8, p3);
      acc0 = __builtin_amdgcn_mfma_f32_32x32x16_bf16(vA3, pf, acc0, 0, 0, 0);
      acc1 = __builtin_amdgcn_mfma_f32_32x32x16_bf16(vB3, pf, acc1, 0, 0, 0);
    }

    // prefetch next V (latency covered by next iter's QK + exp/pack)
    vA0 = *(const s16x8*)(pvn);
    vB0 = *(const s16x8*)(pvn + 256);
    vA1 = *(const s16x8*)(pvn + 4096);
    vB1 = *(const s16x8*)(pvn + 4096 + 256);
    vA2 = *(const s16x8*)(pvn + 8192);
    vB2 = *(const s16x8*)(pvn + 8192 + 256);
    vA3 = *(const s16x8*)(pvn + 12288);
    vB3 = *(const s16x8*)(pvn + 12288 + 256);
    kf0 = nk0; kf1 = nk1;
    pk = pkn; pv = pvn;
  }

  // hi-partner combine of l (purely additive)
  lrun += __shfl_xor(lrun, 32);

  // ---------------- merge the two m-halves + epilogue ----------------
  float* mlb = (float*)lds;             // [16 waves][64 lanes]
  mlb[w * 64 + l] = lrun;
  __syncthreads();
  const float L = lrun + mlb[(w ^ 8) * 64 + l];
  __syncthreads();
  char* xch = lds;                      // [8 wu][64 l][128B], swizzled
  const int xbase = (wu * 64 + l) * 128;
  if (h == 1) {
#pragma unroll
    for (int i = 0; i < 8; i++) {
      f32x4 v;
#pragma unroll
      for (int r = 0; r < 4; r++) v[r] = (i >> 2) ? acc1[(i & 3) * 4 + r] : acc0[(i & 3) * 4 + r];
      *(f32x4*)(xch + xbase + ((i * 16) ^ ((l & 7) << 4))) = v;
    }
  }
  __syncthreads();
  if (h == 0) {
    const float invL = 0.1f / L;
    const int n = n0 + nt * 32 + q;
#pragma unroll
    for (int i = 0; i < 8; i++) {
      f32x4 po = *(const f32x4*)(xch + xbase + ((i * 16) ^ ((l & 7) << 4)));
      const int p_ = i & 3;
      const int cbase = cs * 64 + (i >> 2) * 32 + p_ * 8 + hi * 4;
#pragma unroll
      for (int r = 0; r < 4; r++) {
        const float own = (i >> 2) ? acc1[p_ * 4 + r] : acc0[p_ * 4 + r];
        const size_t idx = ((size_t)b * C_ + (cbase + r)) * N_ + n;
        out[idx] = x[idx] + (own + po[r]) * invL;
      }
    }
  }
}

extern "C" void kernel_launch(void* const* d_in, const int* in_sizes, int n_in,
                              void* d_out, int out_size, void* d_ws, size_t ws_size,
                              hipStream_t stream) {
  const float* x  = (const float*)d_in[0];
  const float* w1 = (const float*)d_in[1];
  const float* b1 = (const float*)d_in[2];
  float* out = (float*)d_out;
  short* fT  = (short*)d_ws;                         // [B][N][16] bf16, 512KB
  short* vtP = (short*)((char*)d_ws + 512 * 1024);   // [B][512][256][8] bf16, 8MB
  prep<<<dim3(256), dim3(256), 0, stream>>>(x, w1, b1, fT);
  packv<<<dim3(512), dim3(256), 0, stream>>>(x, vtP);
  flash5<<<dim3(256), dim3(1024), 0, stream>>>(x, vtP, fT, out);
}